// Round 20
// baseline (74.732 us; speedup 1.0000x reference)
//
#include <hip/hip_runtime.h>
#include <hip/hip_bf16.h>
#include <hip/hip_fp16.h>

#define B_    4096
#define ARITY 6
#define EMB   100
#define NF    200
#define FC    1200
#define NROWS (B_*ARITY)      // 24576
#define NPAD  2432            // N rows of W_h (A/C pairs interleaved)
#define BN_EPS 1e-5f
#define KP    224
#define SENT  32768.0f
#define NTW   (NPAD/4/16)     // 38 tiles of 16 N-rows per wave (o-quarter)

typedef _Float16 half8 __attribute__((ext_vector_type(8)));
typedef float f32x4 __attribute__((ext_vector_type(4)));

// ws float offsets
#define MRAW_OFF 0              // m_raw f16 [24576][200] -> 2,457,600 f
#define WH_OFF   2457600        // W_h f16, tile-major coalesced (k3) -> 272,384 f
#define WT_OFF   2729984        // wT  f16 [ks][hi|lo][224][32] swizzled (k1) -> 50,176 f
#define STAT_OFF 2780160        // gshad[16][400]

__device__ __forceinline__ void gload16(const void* g, void* l) {
    __builtin_amdgcn_global_load_lds(
        (const __attribute__((address_space(1))) void*)g,
        (__attribute__((address_space(3))) void*)l, 16, 0, 0);
}

__device__ __forceinline__ float4 ld4(const float* rr, const float* vr, int e) {
    if (e < EMB)        return *(const float4*)&rr[e];
    else if (e < 2*EMB) return *(const float4*)&vr[e - EMB];
    float4 z = {0.f,0.f,0.f,0.f}; return z;
}

// ---------------- k0: weight prep + out init + gshad zero ------------------
// (byte-identical to round 19)
#define K0_W1 (224*28)
#define K0_W2 (K0_W1 + NPAD*28)
#define K0_W3 (K0_W2 + B_)
#define K0_TOT (K0_W3 + 6400)
__launch_bounds__(256)
__global__ void k0_prep(const float* __restrict__ cw, const float* __restrict__ gW,
                        const float* __restrict__ fb,
                        _Float16* __restrict__ wT,
                        _Float16* __restrict__ W_h, float* __restrict__ out,
                        float* __restrict__ gshad)
{
    int id = blockIdx.x * 256 + threadIdx.x;
    if (id < K0_W1) {
        int f = id / 28, s = id - f*28;
        int ks = s >> 2, ls = s & 3, key = (f >> 1) & 3;
        int off = ks*14336 + f*32 + ((ls ^ key)*8);
        half8 h, l;
        #pragma unroll
        for (int j = 0; j < 8; ++j) {
            int k = s*8 + j;
            float v = (f < NF && k < NF) ? cw[f*NF + k] : 0.f;
            _Float16 hi = (_Float16)v;
            h[j] = hi; l[j] = (_Float16)(v - (float)hi);
        }
        *(half8*)&wT[off] = h;
        *(half8*)&wT[off + 7168] = l;
    } else if (id < K0_W2) {
        int id2 = id - K0_W1;
        int n = id2 / 28, s = id2 - n*28;
        int o = n >> 1, hf = n & 1;
        int off = (n >> 4)*3584 + (s >> 2)*512 + (n & 15)*32 + (s & 3)*8;
        half8 h;
        #pragma unroll
        for (int j = 0; j < 8; ++j) {
            int k = s*8 + j;
            float v = 0.f;
            if (k < NF && n < 2*FC) v = gW[(size_t)o*400 + hf*200 + k];
            if (k == NF) v = SENT;
            h[j] = (_Float16)v;
        }
        *(half8*)&W_h[off] = h;
    } else if (id < K0_W3) {
        out[id - K0_W2] = fb[0];
    } else if (id < K0_TOT) {
        gshad[id - K0_W3] = 0.f;
    }
}

// ---------------- k1: gather + split-f16 MFMA conv + stats -----------------
// (byte-identical to round 19 -- single-buffer staging, 5 blocks/CU)
__launch_bounds__(256)
__global__ void k1_mfma(const int* __restrict__ x,
                        const float* __restrict__ er,
                        const float* __restrict__ ev,
                        const _Float16* __restrict__ wT,
                        const float* __restrict__ cb,
                        _Float16* __restrict__ m_raw,
                        float* __restrict__ gshad)
{
    __shared__ __align__(16) char smem[30528];
    float* s_sum = (float*)(smem + 28672);
    float* s_sq  = (float*)(smem + 29472);
    int*   s_ri  = (int*)(smem + 30272);
    int*   s_vi  = (int*)(smem + 30400);

    const int t = threadIdx.x, lane = t & 63, wave = t >> 6;
    const int wm = wave >> 1, wn = wave & 1;
    const int R0 = blockIdx.x * 32;
    const int q = lane >> 4, cx = lane & 15;
    const int rdsw = (q ^ ((cx >> 1) & 3)) * 8;

    if (t < 32) {
        int R = R0 + t, b = R / ARITY, a = R - b * ARITY;
        bool is64 = ((x[1] | x[3] | x[5] | x[7]) == 0);
        int base = b * (2*ARITY) + 2*a;
        s_ri[t] = is64 ? x[2*base]     : x[base];
        s_vi[t] = is64 ? x[2*base + 2] : x[base + 1];
    }
    if (t < NF) { s_sum[t] = 0.f; s_sq[t] = 0.f; }
    __syncthreads();

    {
        _Float16* s_ahi = (_Float16*)smem;          // 32x224
        _Float16* s_alo = s_ahi + 7168;
        for (int c = t; c < 896; c += 256) {
            int row = c / 28, s = c - row*28;
            int key = (row >> 1) & 3;
            int col = (s >> 2)*32 + ((s & 3) ^ key)*8;
            const float* rr = er + (size_t)s_ri[row] * EMB;
            const float* vr = ev + (size_t)s_vi[row] * EMB;
            int e0 = s*8;
            float4 v0 = ld4(rr, vr, e0);
            float4 v1 = ld4(rr, vr, e0 + 4);
            half8 hi, lo;
            hi[0]=(_Float16)v0.x; lo[0]=(_Float16)(v0.x-(float)hi[0]);
            hi[1]=(_Float16)v0.y; lo[1]=(_Float16)(v0.y-(float)hi[1]);
            hi[2]=(_Float16)v0.z; lo[2]=(_Float16)(v0.z-(float)hi[2]);
            hi[3]=(_Float16)v0.w; lo[3]=(_Float16)(v0.w-(float)hi[3]);
            hi[4]=(_Float16)v1.x; lo[4]=(_Float16)(v1.x-(float)hi[4]);
            hi[5]=(_Float16)v1.y; lo[5]=(_Float16)(v1.y-(float)hi[5]);
            hi[6]=(_Float16)v1.z; lo[6]=(_Float16)(v1.z-(float)hi[6]);
            hi[7]=(_Float16)v1.w; lo[7]=(_Float16)(v1.w-(float)hi[7]);
            *(half8*)&s_ahi[row*KP + col] = hi;
            *(half8*)&s_alo[row*KP + col] = lo;
        }
    }
    __syncthreads();

    f32x4 ah[7], al[7];
    {
        const _Float16* s_ahi = (const _Float16*)smem;
        const _Float16* s_alo = s_ahi + 7168;
        int arow = wm*16 + cx;
        #pragma unroll
        for (int ks = 0; ks < 7; ++ks) {
            ah[ks] = *(const f32x4*)&s_ahi[arow*KP + ks*32 + rdsw];
            al[ks] = *(const f32x4*)&s_alo[arow*KP + ks*32 + rdsw];
            asm volatile("" : "+v"(ah[ks]), "+v"(al[ks]));
        }
    }
    __syncthreads();

    #define STAGE_W(KS_) do {                                                \
        const char* _src = (const char*)wT + (size_t)(KS_) * 28672;          \
        _Pragma("unroll")                                                    \
        for (int _i = 0; _i < 7; ++_i) {                                     \
            int _j = wave + 4*_i;                                            \
            gload16(_src + (size_t)(_j*64 + lane)*16, smem + _j*1024);       \
        }                                                                    \
    } while (0)

    f32x4 acc[7];
    #pragma unroll
    for (int nf = 0; nf < 7; ++nf) acc[nf] = (f32x4){0.f,0.f,0.f,0.f};

    for (int ks = 0; ks < 7; ++ks) {
        STAGE_W(ks);
        __syncthreads();

        const _Float16* wb = (const _Float16*)smem;
        #pragma unroll
        for (int nf = 0; nf < 7; ++nf) {
            int rb = (wn*112 + nf*16 + cx)*32 + rdsw;
            half8 bh = *(const half8*)&wb[rb];
            half8 bl = *(const half8*)&wb[7168 + rb];
            acc[nf] = __builtin_amdgcn_mfma_f32_16x16x32_f16(
                __builtin_bit_cast(half8, ah[ks]), bh, acc[nf], 0,0,0);
            acc[nf] = __builtin_amdgcn_mfma_f32_16x16x32_f16(
                __builtin_bit_cast(half8, ah[ks]), bl, acc[nf], 0,0,0);
            acc[nf] = __builtin_amdgcn_mfma_f32_16x16x32_f16(
                __builtin_bit_cast(half8, al[ks]), bh, acc[nf], 0,0,0);
        }
        __syncthreads();
    }

    #pragma unroll
    for (int nf = 0; nf < 7; ++nf) {
        int f = wn*112 + nf*16 + cx;
        bool valid = (f < NF);
        float bias = valid ? cb[f] : 0.f;
        float ps = 0.f, pq = 0.f;
        #pragma unroll
        for (int reg = 0; reg < 4; ++reg) {
            float vv = acc[nf][reg] + bias;
            if (valid) {
                int R = R0 + wm*16 + q*4 + reg;
                m_raw[(size_t)R*NF + f] = (_Float16)vv;
                ps += vv; pq += vv*vv;
            }
        }
        ps += __shfl_xor(ps, 16); ps += __shfl_xor(ps, 32);
        pq += __shfl_xor(pq, 16); pq += __shfl_xor(pq, 32);
        if (valid && q == 0) { atomicAdd(&s_sum[f], ps); atomicAdd(&s_sq[f], pq); }
    }
    __syncthreads();
    if (t < NF) {
        float* g = gshad + (blockIdx.x & 15) * 400;
        atomicAdd(&g[t], s_sum[t]);
        atomicAdd(&g[t + 200], s_sq[t]);
    }
}

// ---------------- k3: 48-row blocks, SINGLE bv buffer -> true 3 waves/SIMD -
// Round-19 post-mortem: (256,3) was met by moving regs to AGPRs, but the
// UNIFIED file (VGPR+AGPR ~172) still capped us at 2 waves/SIMD. Dropping
// the bv double-buffer (prefetch depth 1->0; depth was null at 1,2,3) frees
// 28 regs: av 84(AGPR) + bv 28 + acc 12 + addr ~25 = ~150 total -> 3
// waves/SIMD for real. k1's r18 lesson applied to k3: TLP > per-wave ILP.
// LDS: A 21504 | gbfw2 @21504 (9728) | scsh @31232 (1792) = 33024.
__launch_bounds__(256, 3)
__global__ void k3_mfma(const _Float16* __restrict__ m_raw,
                        const float* __restrict__ gshad,
                        const float* __restrict__ gamma,
                        const float* __restrict__ beta,
                        const _Float16* __restrict__ W_h,
                        const float* __restrict__ gb,
                        const float* __restrict__ fW,
                        float* __restrict__ out)
{
    __shared__ __align__(16) char smem[33024];
    float2* gbfw2 = (float2*)(smem + 21504);
    float*  scsh  = (float*)(smem + 31232);

    const int t = threadIdx.x, lane = t & 63, wave = t >> 6;
    const int q = lane >> 4, cx = lane & 15;
    const int rdsw = (q ^ ((cx >> 1) & 3)) * 8;
    const int rot = (blockIdx.x * 7) % NTW;

    // ---- inlined BN finalize ----
    if (t < 224) {
        float sc = 0.f, sh = 0.f;
        if (t < NF) {
            float s = 0.f, qq = 0.f;
            #pragma unroll
            for (int c = 0; c < 16; ++c) { s += gshad[c*400 + t]; qq += gshad[c*400 + 200 + t]; }
            float inv = 1.0f / (float)NROWS;
            float mu  = s * inv;
            float var = qq * inv - mu*mu;
            float rs  = rsqrtf(var + BN_EPS);
            sc = rs * gamma[t];
            sh = beta[t] - mu*sc;
        }
        scsh[t] = sc; scsh[224 + t] = sh;
    }
    for (int i = t; i < 1216; i += 256) {
        float g = (i < FC) ? gb[i] : 0.f;
        float f = (i < FC) ? fW[i] : 0.f;
        gbfw2[i] = make_float2(g, f);
    }
    __syncthreads();

    // ---- build swizzled A panel (48 REAL rows x 224 f16) ----
    {
        _Float16* sa = (_Float16*)smem;
        for (int c = t; c < 1344; c += 256) {
            int row = c / 28, s = c - row*28;
            int key = (row >> 1) & 3;
            int col = (s >> 2)*32 + ((s & 3) ^ key)*8;
            half8 o;
            #pragma unroll
            for (int j = 0; j < 8; ++j) o[j] = (_Float16)0.f;
            if (s < 25) {
                int R = blockIdx.x*48 + row;
                half8 in = *(const half8*)&m_raw[(size_t)R*NF + s*8];
                #pragma unroll
                for (int j = 0; j < 8; ++j) {
                    int k = s*8 + j;
                    o[j] = (_Float16)fmaxf((float)in[j]*scsh[k] + scsh[224+k], 0.f);
                }
            }
            *(half8*)&sa[row*KP + col] = o;
        }
    }
    __syncthreads();

    // ---- hoist A fragments (3 mf x 7 ks) ----
    f32x4 av[3][7];
    {
        const _Float16* sa = (const _Float16*)smem;
        #pragma unroll
        for (int mf = 0; mf < 3; ++mf) {
            int row = mf*16 + cx;
            #pragma unroll
            for (int ks = 0; ks < 7; ++ks)
                av[mf][ks] = *(const f32x4*)&sa[row*KP + ks*32 + rdsw];
        }
    }

    const int nbase = wave * (NPAD/4);
    const char* wsrc = (const char*)W_h + (size_t)nbase * 448;
    const int boff = cx*64 + q*16;

    #define PHYS(L_) (((L_) + rot) >= NTW ? ((L_) + rot) - NTW : ((L_) + rot))

    #define LOADT(BV_, L_) do {                                              \
        int _nt = PHYS(L_);                                                  \
        const char* _b = wsrc + (size_t)_nt*7168 + boff;                     \
        _Pragma("unroll")                                                    \
        for (int _k = 0; _k < 7; ++_k)                                       \
            BV_[_k] = *(const f32x4*)(_b + _k*1024);                         \
    } while (0)

    #define MFMAT(BV_, ACC_) do {                                            \
        _Pragma("unroll")                                                    \
        for (int _m = 0; _m < 3; ++_m) ACC_[_m] = (f32x4){0.f,0.f,0.f,0.f};  \
        _Pragma("unroll")                                                    \
        for (int _k = 0; _k < 7; ++_k) {                                     \
            _Pragma("unroll")                                                \
            for (int _m = 0; _m < 3; ++_m)                                   \
                ACC_[_m] = __builtin_amdgcn_mfma_f32_16x16x32_f16(           \
                    __builtin_bit_cast(half8, av[_m][_k]),                   \
                    __builtin_bit_cast(half8, BV_[_k]), ACC_[_m], 0, 0, 0);  \
        }                                                                    \
    } while (0)

    float preg16 = 0.f, preg48 = 0.f;

    #define EPI(ACC_, L_) do {                                               \
        float _h0l = fminf(ACC_[0][0], ACC_[0][1]);                          \
        float _h0h = fminf(ACC_[0][2], ACC_[0][3]);                          \
        float _h1l = fminf(ACC_[1][0], ACC_[1][1]);                          \
        float _h1h = fminf(ACC_[1][2], ACC_[1][3]);                          \
        float _h2l = fminf(ACC_[2][0], ACC_[2][1]);                          \
        float _h2h = fminf(ACC_[2][2], ACC_[2][3]);                          \
        float _f0 = fminf(_h0l, _h0h);                                       \
        float _f1 = fminf(_h1l, _h1h);                                       \
        float _f2 = fminf(_h2l, _h2h);                                       \
        float _u16 = (q==0) ? _h1h : (q==1) ? _h0l : (q==2) ? _h2h : _h1l;   \
        float _u48 = (q==0) ? _h1l : (q==1) ? _h0h : (q==2) ? _h2l : _h1h;   \
        float _F16 = (q==0) ? _f0 : (q==3) ? _f2 : _f1;                      \
        float _F48 = (q<=1) ? _f2 : _f0;                                     \
        float _v16 = fminf(_F16, __shfl_xor(_u16, 16));                      \
        float _v48 = fminf(_F48, __shfl_xor(_u48, 48));                      \
        float _vp16 = _v16 + __shfl_xor(_v16, 1);                            \
        float _vp48 = _v48 + __shfl_xor(_v48, 1);                            \
        float2 _gf = gbfw2[(nbase + PHYS(L_)*16 + cx) >> 1];                 \
        if ((cx & 1) == 0) {                                                 \
            preg16 += fmaxf(_vp16 + _gf.x, 0.f) * _gf.y;                     \
            preg48 += fmaxf(_vp48 + _gf.x, 0.f) * _gf.y;                     \
        }                                                                    \
    } while (0)

    f32x4 bv[7];
    f32x4 acc[3];

    for (int L = 0; L < NTW; ++L) {
        LOADT(bv, L);
        MFMAT(bv, acc);
        EPI(acc, L);
    }

    preg16 += __shfl_xor(preg16, 1); preg16 += __shfl_xor(preg16, 2);
    preg16 += __shfl_xor(preg16, 4); preg16 += __shfl_xor(preg16, 8);
    preg48 += __shfl_xor(preg48, 1); preg48 += __shfl_xor(preg48, 2);
    preg48 += __shfl_xor(preg48, 4); preg48 += __shfl_xor(preg48, 8);
    if (cx == 0) {
        int b16 = (q==0) ? 0 : (q==1) ? 3 : (q==2) ? 4 : 7;
        int b48 = (q==0) ? 5 : (q==1) ? 6 : (q==2) ? 1 : 2;
        atomicAdd(&out[blockIdx.x*8 + b16], preg16);
        atomicAdd(&out[blockIdx.x*8 + b48], preg48);
    }
}

extern "C" void kernel_launch(void* const* d_in, const int* in_sizes, int n_in,
                              void* d_out, int out_size, void* d_ws, size_t ws_size,
                              hipStream_t stream)
{
    const int*   x   = (const int*)  d_in[0];
    const float* er  = (const float*)d_in[1];
    const float* ev  = (const float*)d_in[2];
    const float* cw  = (const float*)d_in[3];
    const float* cb  = (const float*)d_in[4];
    const float* gam = (const float*)d_in[5];
    const float* bet = (const float*)d_in[6];
    const float* gW  = (const float*)d_in[7];
    const float* gb  = (const float*)d_in[8];
    const float* fW  = (const float*)d_in[9];
    const float* fb  = (const float*)d_in[10];

    float* ws = (float*)d_ws;
    _Float16* m_raw = (_Float16*)(ws + MRAW_OFF);
    _Float16* W_h   = (_Float16*)(ws + WH_OFF);
    _Float16* wT    = (_Float16*)(ws + WT_OFF);
    float* gshad    = ws + STAT_OFF;
    float* out      = (float*)d_out;

    k0_prep<<<(K0_TOT + 255)/256, 256, 0, stream>>>(cw, gW, fb, wT, W_h, out, gshad);
    k1_mfma<<<NROWS/32, 256, 0, stream>>>(x, er, ev, wT, cb, m_raw, gshad);
    k3_mfma<<<NROWS/48, 256, 0, stream>>>(m_raw, gshad, gam, bet, W_h, gb, fW, out);
}

// Round 21
// 68.288 us; speedup vs baseline: 1.0944x; 1.0944x over previous
//
#include <hip/hip_runtime.h>
#include <hip/hip_bf16.h>
#include <hip/hip_fp16.h>

#define B_    4096
#define ARITY 6
#define EMB   100
#define NF    200
#define FC    1200
#define NROWS (B_*ARITY)      // 24576
#define NPAD  2432            // N rows of W_h (A/C pairs interleaved)
#define BN_EPS 1e-5f
#define KP    224
#define SENT  32768.0f
#define NTW8  19              // tiles of 16 N-rows per wave (o-eighth)

typedef _Float16 half8 __attribute__((ext_vector_type(8)));
typedef float f32x4 __attribute__((ext_vector_type(4)));

// ws float offsets
#define MRAW_OFF 0              // m_raw f16 [24576][200] -> 2,457,600 f
#define WH_OFF   2457600        // W_h f16, tile-major coalesced (k3) -> 272,384 f
#define WT_OFF   2729984        // wT  f16 [ks][hi|lo][224][32] swizzled (k1) -> 50,176 f
#define STAT_OFF 2780160        // gshad[16][400]

__device__ __forceinline__ void gload16(const void* g, void* l) {
    __builtin_amdgcn_global_load_lds(
        (const __attribute__((address_space(1))) void*)g,
        (__attribute__((address_space(3))) void*)l, 16, 0, 0);
}

__device__ __forceinline__ float4 ld4(const float* rr, const float* vr, int e) {
    if (e < EMB)        return *(const float4*)&rr[e];
    else if (e < 2*EMB) return *(const float4*)&vr[e - EMB];
    float4 z = {0.f,0.f,0.f,0.f}; return z;
}

// ---------------- k0: weight prep + out init + gshad zero ------------------
// (byte-identical to round 19)
#define K0_W1 (224*28)
#define K0_W2 (K0_W1 + NPAD*28)
#define K0_W3 (K0_W2 + B_)
#define K0_TOT (K0_W3 + 6400)
__launch_bounds__(256)
__global__ void k0_prep(const float* __restrict__ cw, const float* __restrict__ gW,
                        const float* __restrict__ fb,
                        _Float16* __restrict__ wT,
                        _Float16* __restrict__ W_h, float* __restrict__ out,
                        float* __restrict__ gshad)
{
    int id = blockIdx.x * 256 + threadIdx.x;
    if (id < K0_W1) {
        int f = id / 28, s = id - f*28;
        int ks = s >> 2, ls = s & 3, key = (f >> 1) & 3;
        int off = ks*14336 + f*32 + ((ls ^ key)*8);
        half8 h, l;
        #pragma unroll
        for (int j = 0; j < 8; ++j) {
            int k = s*8 + j;
            float v = (f < NF && k < NF) ? cw[f*NF + k] : 0.f;
            _Float16 hi = (_Float16)v;
            h[j] = hi; l[j] = (_Float16)(v - (float)hi);
        }
        *(half8*)&wT[off] = h;
        *(half8*)&wT[off + 7168] = l;
    } else if (id < K0_W2) {
        int id2 = id - K0_W1;
        int n = id2 / 28, s = id2 - n*28;
        int o = n >> 1, hf = n & 1;
        int off = (n >> 4)*3584 + (s >> 2)*512 + (n & 15)*32 + (s & 3)*8;
        half8 h;
        #pragma unroll
        for (int j = 0; j < 8; ++j) {
            int k = s*8 + j;
            float v = 0.f;
            if (k < NF && n < 2*FC) v = gW[(size_t)o*400 + hf*200 + k];
            if (k == NF) v = SENT;
            h[j] = (_Float16)v;
        }
        *(half8*)&W_h[off] = h;
    } else if (id < K0_W3) {
        out[id - K0_W2] = fb[0];
    } else if (id < K0_TOT) {
        gshad[id - K0_W3] = 0.f;
    }
}

// ---------------- k1: gather + split-f16 MFMA conv + stats -----------------
// (byte-identical to round 19 -- single-buffer staging, 5 blocks/CU)
__launch_bounds__(256)
__global__ void k1_mfma(const int* __restrict__ x,
                        const float* __restrict__ er,
                        const float* __restrict__ ev,
                        const _Float16* __restrict__ wT,
                        const float* __restrict__ cb,
                        _Float16* __restrict__ m_raw,
                        float* __restrict__ gshad)
{
    __shared__ __align__(16) char smem[30528];
    float* s_sum = (float*)(smem + 28672);
    float* s_sq  = (float*)(smem + 29472);
    int*   s_ri  = (int*)(smem + 30272);
    int*   s_vi  = (int*)(smem + 30400);

    const int t = threadIdx.x, lane = t & 63, wave = t >> 6;
    const int wm = wave >> 1, wn = wave & 1;
    const int R0 = blockIdx.x * 32;
    const int q = lane >> 4, cx = lane & 15;
    const int rdsw = (q ^ ((cx >> 1) & 3)) * 8;

    if (t < 32) {
        int R = R0 + t, b = R / ARITY, a = R - b * ARITY;
        bool is64 = ((x[1] | x[3] | x[5] | x[7]) == 0);
        int base = b * (2*ARITY) + 2*a;
        s_ri[t] = is64 ? x[2*base]     : x[base];
        s_vi[t] = is64 ? x[2*base + 2] : x[base + 1];
    }
    if (t < NF) { s_sum[t] = 0.f; s_sq[t] = 0.f; }
    __syncthreads();

    {
        _Float16* s_ahi = (_Float16*)smem;          // 32x224
        _Float16* s_alo = s_ahi + 7168;
        for (int c = t; c < 896; c += 256) {
            int row = c / 28, s = c - row*28;
            int key = (row >> 1) & 3;
            int col = (s >> 2)*32 + ((s & 3) ^ key)*8;
            const float* rr = er + (size_t)s_ri[row] * EMB;
            const float* vr = ev + (size_t)s_vi[row] * EMB;
            int e0 = s*8;
            float4 v0 = ld4(rr, vr, e0);
            float4 v1 = ld4(rr, vr, e0 + 4);
            half8 hi, lo;
            hi[0]=(_Float16)v0.x; lo[0]=(_Float16)(v0.x-(float)hi[0]);
            hi[1]=(_Float16)v0.y; lo[1]=(_Float16)(v0.y-(float)hi[1]);
            hi[2]=(_Float16)v0.z; lo[2]=(_Float16)(v0.z-(float)hi[2]);
            hi[3]=(_Float16)v0.w; lo[3]=(_Float16)(v0.w-(float)hi[3]);
            hi[4]=(_Float16)v1.x; lo[4]=(_Float16)(v1.x-(float)hi[4]);
            hi[5]=(_Float16)v1.y; lo[5]=(_Float16)(v1.y-(float)hi[5]);
            hi[6]=(_Float16)v1.z; lo[6]=(_Float16)(v1.z-(float)hi[6]);
            hi[7]=(_Float16)v1.w; lo[7]=(_Float16)(v1.w-(float)hi[7]);
            *(half8*)&s_ahi[row*KP + col] = hi;
            *(half8*)&s_alo[row*KP + col] = lo;
        }
    }
    __syncthreads();

    f32x4 ah[7], al[7];
    {
        const _Float16* s_ahi = (const _Float16*)smem;
        const _Float16* s_alo = s_ahi + 7168;
        int arow = wm*16 + cx;
        #pragma unroll
        for (int ks = 0; ks < 7; ++ks) {
            ah[ks] = *(const f32x4*)&s_ahi[arow*KP + ks*32 + rdsw];
            al[ks] = *(const f32x4*)&s_alo[arow*KP + ks*32 + rdsw];
            asm volatile("" : "+v"(ah[ks]), "+v"(al[ks]));
        }
    }
    __syncthreads();

    #define STAGE_W(KS_) do {                                                \
        const char* _src = (const char*)wT + (size_t)(KS_) * 28672;          \
        _Pragma("unroll")                                                    \
        for (int _i = 0; _i < 7; ++_i) {                                     \
            int _j = wave + 4*_i;                                            \
            gload16(_src + (size_t)(_j*64 + lane)*16, smem + _j*1024);       \
        }                                                                    \
    } while (0)

    f32x4 acc[7];
    #pragma unroll
    for (int nf = 0; nf < 7; ++nf) acc[nf] = (f32x4){0.f,0.f,0.f,0.f};

    for (int ks = 0; ks < 7; ++ks) {
        STAGE_W(ks);
        __syncthreads();

        const _Float16* wb = (const _Float16*)smem;
        #pragma unroll
        for (int nf = 0; nf < 7; ++nf) {
            int rb = (wn*112 + nf*16 + cx)*32 + rdsw;
            half8 bh = *(const half8*)&wb[rb];
            half8 bl = *(const half8*)&wb[7168 + rb];
            acc[nf] = __builtin_amdgcn_mfma_f32_16x16x32_f16(
                __builtin_bit_cast(half8, ah[ks]), bh, acc[nf], 0,0,0);
            acc[nf] = __builtin_amdgcn_mfma_f32_16x16x32_f16(
                __builtin_bit_cast(half8, ah[ks]), bl, acc[nf], 0,0,0);
            acc[nf] = __builtin_amdgcn_mfma_f32_16x16x32_f16(
                __builtin_bit_cast(half8, al[ks]), bh, acc[nf], 0,0,0);
        }
        __syncthreads();
    }

    #pragma unroll
    for (int nf = 0; nf < 7; ++nf) {
        int f = wn*112 + nf*16 + cx;
        bool valid = (f < NF);
        float bias = valid ? cb[f] : 0.f;
        float ps = 0.f, pq = 0.f;
        #pragma unroll
        for (int reg = 0; reg < 4; ++reg) {
            float vv = acc[nf][reg] + bias;
            if (valid) {
                int R = R0 + wm*16 + q*4 + reg;
                m_raw[(size_t)R*NF + f] = (_Float16)vv;
                ps += vv; pq += vv*vv;
            }
        }
        ps += __shfl_xor(ps, 16); ps += __shfl_xor(ps, 32);
        pq += __shfl_xor(pq, 16); pq += __shfl_xor(pq, 32);
        if (valid && q == 0) { atomicAdd(&s_sum[f], ps); atomicAdd(&s_sq[f], pq); }
    }
    __syncthreads();
    if (t < NF) {
        float* g = gshad + (blockIdx.x & 15) * 400;
        atomicAdd(&g[t], s_sum[t]);
        atomicAdd(&g[t + 200], s_sq[t]);
    }
}

// ---------------- k3: N-SPLIT grid 1024 -> true 12 waves/CU ----------------
// r20 post-mortem: grid 512 = 2 blocks/CU caps occupancy at 8 waves/CU no
// matter the register count -- every TLP attempt was grid-capped. Fix: each
// 48-row M-block spawns TWO blocks (nsplit = o-half); waves own o-EIGHTHS
// (19 tiles of 16). Grid 1024 = 4 blocks/CU assigned; register diet (av 84
// AGPR + single bv 28 + acc 12 + addr ~25 = ~150 unified) -> 3 blocks/CU
// resident = 12 waves/CU. Sum-over-o splits linearly across blocks (out
// accumulated via atomics); min-over-arity stays block-local (all 6 rows of
// each batch present). Only fp32 sum order changes (~1e-6).
// LDS: A 21504 | gbfw2 @21504 (9728) | scsh @31232 (1792) = 33024 (x3 = 99KB).
__launch_bounds__(256, 3)
__global__ void k3_mfma(const _Float16* __restrict__ m_raw,
                        const float* __restrict__ gshad,
                        const float* __restrict__ gamma,
                        const float* __restrict__ beta,
                        const _Float16* __restrict__ W_h,
                        const float* __restrict__ gb,
                        const float* __restrict__ fW,
                        float* __restrict__ out)
{
    __shared__ __align__(16) char smem[33024];
    float2* gbfw2 = (float2*)(smem + 21504);
    float*  scsh  = (float*)(smem + 31232);

    const int t = threadIdx.x, lane = t & 63, wave = t >> 6;
    const int q = lane >> 4, cx = lane & 15;
    const int rdsw = (q ^ ((cx >> 1) & 3)) * 8;
    const int mblk = blockIdx.x >> 1;          // 0..511 : which 48 M-rows
    const int nsplit = blockIdx.x & 1;         // 0..1   : which o-half
    const int rot = (blockIdx.x * 7) % NTW8;

    // ---- inlined BN finalize ----
    if (t < 224) {
        float sc = 0.f, sh = 0.f;
        if (t < NF) {
            float s = 0.f, qq = 0.f;
            #pragma unroll
            for (int c = 0; c < 16; ++c) { s += gshad[c*400 + t]; qq += gshad[c*400 + 200 + t]; }
            float inv = 1.0f / (float)NROWS;
            float mu  = s * inv;
            float var = qq * inv - mu*mu;
            float rs  = rsqrtf(var + BN_EPS);
            sc = rs * gamma[t];
            sh = beta[t] - mu*sc;
        }
        scsh[t] = sc; scsh[224 + t] = sh;
    }
    for (int i = t; i < 1216; i += 256) {
        float g = (i < FC) ? gb[i] : 0.f;
        float f = (i < FC) ? fW[i] : 0.f;
        gbfw2[i] = make_float2(g, f);
    }
    __syncthreads();

    // ---- build swizzled A panel (48 REAL rows x 224 f16) ----
    {
        _Float16* sa = (_Float16*)smem;
        for (int c = t; c < 1344; c += 256) {
            int row = c / 28, s = c - row*28;
            int key = (row >> 1) & 3;
            int col = (s >> 2)*32 + ((s & 3) ^ key)*8;
            half8 o;
            #pragma unroll
            for (int j = 0; j < 8; ++j) o[j] = (_Float16)0.f;
            if (s < 25) {
                int R = mblk*48 + row;
                half8 in = *(const half8*)&m_raw[(size_t)R*NF + s*8];
                #pragma unroll
                for (int j = 0; j < 8; ++j) {
                    int k = s*8 + j;
                    o[j] = (_Float16)fmaxf((float)in[j]*scsh[k] + scsh[224+k], 0.f);
                }
            }
            *(half8*)&sa[row*KP + col] = o;
        }
    }
    __syncthreads();

    // ---- hoist A fragments (3 mf x 7 ks) ----
    f32x4 av[3][7];
    {
        const _Float16* sa = (const _Float16*)smem;
        #pragma unroll
        for (int mf = 0; mf < 3; ++mf) {
            int row = mf*16 + cx;
            #pragma unroll
            for (int ks = 0; ks < 7; ++ks)
                av[mf][ks] = *(const f32x4*)&sa[row*KP + ks*32 + rdsw];
        }
    }

    const int nbase = nsplit*(NPAD/2) + wave*(NPAD/8);   // o-eighth: 304 rows
    const char* wsrc = (const char*)W_h + (size_t)nbase * 448;
    const int boff = cx*64 + q*16;

    #define PHYS(L_) (((L_) + rot) >= NTW8 ? ((L_) + rot) - NTW8 : ((L_) + rot))

    #define LOADT(BV_, L_) do {                                              \
        int _nt = PHYS(L_);                                                  \
        const char* _b = wsrc + (size_t)_nt*7168 + boff;                     \
        _Pragma("unroll")                                                    \
        for (int _k = 0; _k < 7; ++_k)                                       \
            BV_[_k] = *(const f32x4*)(_b + _k*1024);                         \
    } while (0)

    #define MFMAT(BV_, ACC_) do {                                            \
        _Pragma("unroll")                                                    \
        for (int _m = 0; _m < 3; ++_m) ACC_[_m] = (f32x4){0.f,0.f,0.f,0.f};  \
        _Pragma("unroll")                                                    \
        for (int _k = 0; _k < 7; ++_k) {                                     \
            _Pragma("unroll")                                                \
            for (int _m = 0; _m < 3; ++_m)                                   \
                ACC_[_m] = __builtin_amdgcn_mfma_f32_16x16x32_f16(           \
                    __builtin_bit_cast(half8, av[_m][_k]),                   \
                    __builtin_bit_cast(half8, BV_[_k]), ACC_[_m], 0, 0, 0);  \
        }                                                                    \
    } while (0)

    float preg16 = 0.f, preg48 = 0.f;

    #define EPI(ACC_, L_) do {                                               \
        float _h0l = fminf(ACC_[0][0], ACC_[0][1]);                          \
        float _h0h = fminf(ACC_[0][2], ACC_[0][3]);                          \
        float _h1l = fminf(ACC_[1][0], ACC_[1][1]);                          \
        float _h1h = fminf(ACC_[1][2], ACC_[1][3]);                          \
        float _h2l = fminf(ACC_[2][0], ACC_[2][1]);                          \
        float _h2h = fminf(ACC_[2][2], ACC_[2][3]);                          \
        float _f0 = fminf(_h0l, _h0h);                                       \
        float _f1 = fminf(_h1l, _h1h);                                       \
        float _f2 = fminf(_h2l, _h2h);                                       \
        float _u16 = (q==0) ? _h1h : (q==1) ? _h0l : (q==2) ? _h2h : _h1l;   \
        float _u48 = (q==0) ? _h1l : (q==1) ? _h0h : (q==2) ? _h2l : _h1h;   \
        float _F16 = (q==0) ? _f0 : (q==3) ? _f2 : _f1;                      \
        float _F48 = (q<=1) ? _f2 : _f0;                                     \
        float _v16 = fminf(_F16, __shfl_xor(_u16, 16));                      \
        float _v48 = fminf(_F48, __shfl_xor(_u48, 48));                      \
        float _vp16 = _v16 + __shfl_xor(_v16, 1);                            \
        float _vp48 = _v48 + __shfl_xor(_v48, 1);                            \
        float2 _gf = gbfw2[(nbase + PHYS(L_)*16 + cx) >> 1];                 \
        if ((cx & 1) == 0) {                                                 \
            preg16 += fmaxf(_vp16 + _gf.x, 0.f) * _gf.y;                     \
            preg48 += fmaxf(_vp48 + _gf.x, 0.f) * _gf.y;                     \
        }                                                                    \
    } while (0)

    f32x4 bv[7];
    f32x4 acc[3];

    for (int L = 0; L < NTW8; ++L) {
        LOADT(bv, L);
        MFMAT(bv, acc);
        EPI(acc, L);
    }

    preg16 += __shfl_xor(preg16, 1); preg16 += __shfl_xor(preg16, 2);
    preg16 += __shfl_xor(preg16, 4); preg16 += __shfl_xor(preg16, 8);
    preg48 += __shfl_xor(preg48, 1); preg48 += __shfl_xor(preg48, 2);
    preg48 += __shfl_xor(preg48, 4); preg48 += __shfl_xor(preg48, 8);
    if (cx == 0) {
        int b16 = (q==0) ? 0 : (q==1) ? 3 : (q==2) ? 4 : 7;
        int b48 = (q==0) ? 5 : (q==1) ? 6 : (q==2) ? 1 : 2;
        atomicAdd(&out[mblk*8 + b16], preg16);
        atomicAdd(&out[mblk*8 + b48], preg48);
    }
}

extern "C" void kernel_launch(void* const* d_in, const int* in_sizes, int n_in,
                              void* d_out, int out_size, void* d_ws, size_t ws_size,
                              hipStream_t stream)
{
    const int*   x   = (const int*)  d_in[0];
    const float* er  = (const float*)d_in[1];
    const float* ev  = (const float*)d_in[2];
    const float* cw  = (const float*)d_in[3];
    const float* cb  = (const float*)d_in[4];
    const float* gam = (const float*)d_in[5];
    const float* bet = (const float*)d_in[6];
    const float* gW  = (const float*)d_in[7];
    const float* gb  = (const float*)d_in[8];
    const float* fW  = (const float*)d_in[9];
    const float* fb  = (const float*)d_in[10];

    float* ws = (float*)d_ws;
    _Float16* m_raw = (_Float16*)(ws + MRAW_OFF);
    _Float16* W_h   = (_Float16*)(ws + WH_OFF);
    _Float16* wT    = (_Float16*)(ws + WT_OFF);
    float* gshad    = ws + STAT_OFF;
    float* out      = (float*)d_out;

    k0_prep<<<(K0_TOT + 255)/256, 256, 0, stream>>>(cw, gW, fb, wT, W_h, out, gshad);
    k1_mfma<<<NROWS/32, 256, 0, stream>>>(x, er, ev, wT, cb, m_raw, gshad);
    k3_mfma<<<NROWS/48*2, 256, 0, stream>>>(m_raw, gshad, gam, bet, W_h, gb, fW, out);
}

// Round 22
// 66.769 us; speedup vs baseline: 1.1193x; 1.0228x over previous
//
#include <hip/hip_runtime.h>
#include <hip/hip_bf16.h>
#include <hip/hip_fp16.h>

#define B_    4096
#define ARITY 6
#define EMB   100
#define NF    200
#define FC    1200
#define NROWS (B_*ARITY)      // 24576
#define NPAD  2432            // N rows of W_h (A/C pairs interleaved)
#define BN_EPS 1e-5f
#define KP    224
#define SENT  32768.0f
#define NTW   (NPAD/4/16)     // 38 tiles of 16 N-rows per wave (o-quarter)

typedef _Float16 half8 __attribute__((ext_vector_type(8)));
typedef float f32x4 __attribute__((ext_vector_type(4)));

// ws float offsets
#define MRAW_OFF 0              // m_raw f16 [24576][200] -> 2,457,600 f
#define WH_OFF   2457600        // W_h f16, tile-major coalesced (k3) -> 272,384 f
#define WT_OFF   2729984        // wT  f16 [ks][hi|lo][224][32] swizzled (k1) -> 50,176 f
#define STAT_OFF 2780160        // gshad[16][400]

__device__ __forceinline__ void gload16(const void* g, void* l) {
    __builtin_amdgcn_global_load_lds(
        (const __attribute__((address_space(1))) void*)g,
        (__attribute__((address_space(3))) void*)l, 16, 0, 0);
}

__device__ __forceinline__ float4 ld4(const float* rr, const float* vr, int e) {
    if (e < EMB)        return *(const float4*)&rr[e];
    else if (e < 2*EMB) return *(const float4*)&vr[e - EMB];
    float4 z = {0.f,0.f,0.f,0.f}; return z;
}

// ---------------- k0: weight prep + out init + gshad zero ------------------
#define K0_W1 (224*28)
#define K0_W2 (K0_W1 + NPAD*28)
#define K0_W3 (K0_W2 + B_)
#define K0_TOT (K0_W3 + 6400)
__launch_bounds__(256)
__global__ void k0_prep(const float* __restrict__ cw, const float* __restrict__ gW,
                        const float* __restrict__ fb,
                        _Float16* __restrict__ wT,
                        _Float16* __restrict__ W_h, float* __restrict__ out,
                        float* __restrict__ gshad)
{
    int id = blockIdx.x * 256 + threadIdx.x;
    if (id < K0_W1) {
        int f = id / 28, s = id - f*28;
        int ks = s >> 2, ls = s & 3, key = (f >> 1) & 3;
        int off = ks*14336 + f*32 + ((ls ^ key)*8);
        half8 h, l;
        #pragma unroll
        for (int j = 0; j < 8; ++j) {
            int k = s*8 + j;
            float v = (f < NF && k < NF) ? cw[f*NF + k] : 0.f;
            _Float16 hi = (_Float16)v;
            h[j] = hi; l[j] = (_Float16)(v - (float)hi);
        }
        *(half8*)&wT[off] = h;
        *(half8*)&wT[off + 7168] = l;
    } else if (id < K0_W2) {
        int id2 = id - K0_W1;
        int n = id2 / 28, s = id2 - n*28;
        int o = n >> 1, hf = n & 1;
        int off = (n >> 4)*3584 + (s >> 2)*512 + (n & 15)*32 + (s & 3)*8;
        half8 h;
        #pragma unroll
        for (int j = 0; j < 8; ++j) {
            int k = s*8 + j;
            float v = 0.f;
            if (k < NF && n < 2*FC) v = gW[(size_t)o*400 + hf*200 + k];
            if (k == NF) v = SENT;
            h[j] = (_Float16)v;
        }
        *(half8*)&W_h[off] = h;
    } else if (id < K0_W3) {
        out[id - K0_W2] = fb[0];
    } else if (id < K0_TOT) {
        gshad[id - K0_W3] = 0.f;
    }
}

// ---------------- k1: gather + split-f16 MFMA conv + stats -----------------
// (round-18/19 version verbatim -- single-buffer staging, 5 blocks/CU)
__launch_bounds__(256)
__global__ void k1_mfma(const int* __restrict__ x,
                        const float* __restrict__ er,
                        const float* __restrict__ ev,
                        const _Float16* __restrict__ wT,
                        const float* __restrict__ cb,
                        _Float16* __restrict__ m_raw,
                        float* __restrict__ gshad)
{
    __shared__ __align__(16) char smem[30528];
    float* s_sum = (float*)(smem + 28672);
    float* s_sq  = (float*)(smem + 29472);
    int*   s_ri  = (int*)(smem + 30272);
    int*   s_vi  = (int*)(smem + 30400);

    const int t = threadIdx.x, lane = t & 63, wave = t >> 6;
    const int wm = wave >> 1, wn = wave & 1;
    const int R0 = blockIdx.x * 32;
    const int q = lane >> 4, cx = lane & 15;
    const int rdsw = (q ^ ((cx >> 1) & 3)) * 8;

    if (t < 32) {
        int R = R0 + t, b = R / ARITY, a = R - b * ARITY;
        bool is64 = ((x[1] | x[3] | x[5] | x[7]) == 0);
        int base = b * (2*ARITY) + 2*a;
        s_ri[t] = is64 ? x[2*base]     : x[base];
        s_vi[t] = is64 ? x[2*base + 2] : x[base + 1];
    }
    if (t < NF) { s_sum[t] = 0.f; s_sq[t] = 0.f; }
    __syncthreads();

    {
        _Float16* s_ahi = (_Float16*)smem;          // 32x224
        _Float16* s_alo = s_ahi + 7168;
        for (int c = t; c < 896; c += 256) {
            int row = c / 28, s = c - row*28;
            int key = (row >> 1) & 3;
            int col = (s >> 2)*32 + ((s & 3) ^ key)*8;
            const float* rr = er + (size_t)s_ri[row] * EMB;
            const float* vr = ev + (size_t)s_vi[row] * EMB;
            int e0 = s*8;
            float4 v0 = ld4(rr, vr, e0);
            float4 v1 = ld4(rr, vr, e0 + 4);
            half8 hi, lo;
            hi[0]=(_Float16)v0.x; lo[0]=(_Float16)(v0.x-(float)hi[0]);
            hi[1]=(_Float16)v0.y; lo[1]=(_Float16)(v0.y-(float)hi[1]);
            hi[2]=(_Float16)v0.z; lo[2]=(_Float16)(v0.z-(float)hi[2]);
            hi[3]=(_Float16)v0.w; lo[3]=(_Float16)(v0.w-(float)hi[3]);
            hi[4]=(_Float16)v1.x; lo[4]=(_Float16)(v1.x-(float)hi[4]);
            hi[5]=(_Float16)v1.y; lo[5]=(_Float16)(v1.y-(float)hi[5]);
            hi[6]=(_Float16)v1.z; lo[6]=(_Float16)(v1.z-(float)hi[6]);
            hi[7]=(_Float16)v1.w; lo[7]=(_Float16)(v1.w-(float)hi[7]);
            *(half8*)&s_ahi[row*KP + col] = hi;
            *(half8*)&s_alo[row*KP + col] = lo;
        }
    }
    __syncthreads();

    f32x4 ah[7], al[7];
    {
        const _Float16* s_ahi = (const _Float16*)smem;
        const _Float16* s_alo = s_ahi + 7168;
        int arow = wm*16 + cx;
        #pragma unroll
        for (int ks = 0; ks < 7; ++ks) {
            ah[ks] = *(const f32x4*)&s_ahi[arow*KP + ks*32 + rdsw];
            al[ks] = *(const f32x4*)&s_alo[arow*KP + ks*32 + rdsw];
            asm volatile("" : "+v"(ah[ks]), "+v"(al[ks]));
        }
    }
    __syncthreads();

    #define STAGE_W(KS_) do {                                                \
        const char* _src = (const char*)wT + (size_t)(KS_) * 28672;          \
        _Pragma("unroll")                                                    \
        for (int _i = 0; _i < 7; ++_i) {                                     \
            int _j = wave + 4*_i;                                            \
            gload16(_src + (size_t)(_j*64 + lane)*16, smem + _j*1024);       \
        }                                                                    \
    } while (0)

    f32x4 acc[7];
    #pragma unroll
    for (int nf = 0; nf < 7; ++nf) acc[nf] = (f32x4){0.f,0.f,0.f,0.f};

    for (int ks = 0; ks < 7; ++ks) {
        STAGE_W(ks);
        __syncthreads();

        const _Float16* wb = (const _Float16*)smem;
        #pragma unroll
        for (int nf = 0; nf < 7; ++nf) {
            int rb = (wn*112 + nf*16 + cx)*32 + rdsw;
            half8 bh = *(const half8*)&wb[rb];
            half8 bl = *(const half8*)&wb[7168 + rb];
            acc[nf] = __builtin_amdgcn_mfma_f32_16x16x32_f16(
                __builtin_bit_cast(half8, ah[ks]), bh, acc[nf], 0,0,0);
            acc[nf] = __builtin_amdgcn_mfma_f32_16x16x32_f16(
                __builtin_bit_cast(half8, ah[ks]), bl, acc[nf], 0,0,0);
            acc[nf] = __builtin_amdgcn_mfma_f32_16x16x32_f16(
                __builtin_bit_cast(half8, al[ks]), bh, acc[nf], 0,0,0);
        }
        __syncthreads();
    }

    #pragma unroll
    for (int nf = 0; nf < 7; ++nf) {
        int f = wn*112 + nf*16 + cx;
        bool valid = (f < NF);
        float bias = valid ? cb[f] : 0.f;
        float ps = 0.f, pq = 0.f;
        #pragma unroll
        for (int reg = 0; reg < 4; ++reg) {
            float vv = acc[nf][reg] + bias;
            if (valid) {
                int R = R0 + wm*16 + q*4 + reg;
                m_raw[(size_t)R*NF + f] = (_Float16)vv;
                ps += vv; pq += vv*vv;
            }
        }
        ps += __shfl_xor(ps, 16); ps += __shfl_xor(ps, 32);
        pq += __shfl_xor(pq, 16); pq += __shfl_xor(pq, 32);
        if (valid && q == 0) { atomicAdd(&s_sum[f], ps); atomicAdd(&s_sq[f], pq); }
    }
    __syncthreads();
    if (t < NF) {
        float* g = gshad + (blockIdx.x & 15) * 400;
        atomicAdd(&g[t], s_sum[t]);
        atomicAdd(&g[t + 200], s_sq[t]);
    }
}

// ---------------- k3: 48-row blocks, dbuf + rotation (r19 verbatim, 43us) --
__launch_bounds__(256, 3)
__global__ void k3_mfma(const _Float16* __restrict__ m_raw,
                        const float* __restrict__ gshad,
                        const float* __restrict__ gamma,
                        const float* __restrict__ beta,
                        const _Float16* __restrict__ W_h,
                        const float* __restrict__ gb,
                        const float* __restrict__ fW,
                        float* __restrict__ out)
{
    __shared__ __align__(16) char smem[33024];
    float2* gbfw2 = (float2*)(smem + 21504);
    float*  scsh  = (float*)(smem + 31232);

    const int t = threadIdx.x, lane = t & 63, wave = t >> 6;
    const int q = lane >> 4, cx = lane & 15;
    const int rdsw = (q ^ ((cx >> 1) & 3)) * 8;
    const int rot = (blockIdx.x * 7) % NTW;

    // ---- inlined BN finalize ----
    if (t < 224) {
        float sc = 0.f, sh = 0.f;
        if (t < NF) {
            float s = 0.f, qq = 0.f;
            #pragma unroll
            for (int c = 0; c < 16; ++c) { s += gshad[c*400 + t]; qq += gshad[c*400 + 200 + t]; }
            float inv = 1.0f / (float)NROWS;
            float mu  = s * inv;
            float var = qq * inv - mu*mu;
            float rs  = rsqrtf(var + BN_EPS);
            sc = rs * gamma[t];
            sh = beta[t] - mu*sc;
        }
        scsh[t] = sc; scsh[224 + t] = sh;
    }
    for (int i = t; i < 1216; i += 256) {
        float g = (i < FC) ? gb[i] : 0.f;
        float f = (i < FC) ? fW[i] : 0.f;
        gbfw2[i] = make_float2(g, f);
    }
    __syncthreads();

    // ---- build swizzled A panel (48 REAL rows x 224 f16) ----
    {
        _Float16* sa = (_Float16*)smem;
        for (int c = t; c < 1344; c += 256) {
            int row = c / 28, s = c - row*28;
            int key = (row >> 1) & 3;
            int col = (s >> 2)*32 + ((s & 3) ^ key)*8;
            half8 o;
            #pragma unroll
            for (int j = 0; j < 8; ++j) o[j] = (_Float16)0.f;
            if (s < 25) {
                int R = blockIdx.x*48 + row;
                half8 in = *(const half8*)&m_raw[(size_t)R*NF + s*8];
                #pragma unroll
                for (int j = 0; j < 8; ++j) {
                    int k = s*8 + j;
                    o[j] = (_Float16)fmaxf((float)in[j]*scsh[k] + scsh[224+k], 0.f);
                }
            }
            *(half8*)&sa[row*KP + col] = o;
        }
    }
    __syncthreads();

    // ---- hoist A fragments (3 mf x 7 ks) ----
    f32x4 av[3][7];
    {
        const _Float16* sa = (const _Float16*)smem;
        #pragma unroll
        for (int mf = 0; mf < 3; ++mf) {
            int row = mf*16 + cx;
            #pragma unroll
            for (int ks = 0; ks < 7; ++ks)
                av[mf][ks] = *(const f32x4*)&sa[row*KP + ks*32 + rdsw];
        }
    }

    const int nbase = wave * (NPAD/4);
    const char* wsrc = (const char*)W_h + (size_t)nbase * 448;
    const int boff = cx*64 + q*16;

    #define PHYS(L_) (((L_) + rot) >= NTW ? ((L_) + rot) - NTW : ((L_) + rot))

    #define LOADT(BV_, L_) do {                                              \
        int _nt = PHYS((L_) < NTW ? (L_) : 0);                               \
        const char* _b = wsrc + (size_t)_nt*7168 + boff;                     \
        _Pragma("unroll")                                                    \
        for (int _k = 0; _k < 7; ++_k)                                       \
            BV_[_k] = *(const f32x4*)(_b + _k*1024);                         \
    } while (0)

    #define MFMAT(BV_, ACC_) do {                                            \
        _Pragma("unroll")                                                    \
        for (int _m = 0; _m < 3; ++_m) ACC_[_m] = (f32x4){0.f,0.f,0.f,0.f};  \
        _Pragma("unroll")                                                    \
        for (int _k = 0; _k < 7; ++_k) {                                     \
            _Pragma("unroll")                                                \
            for (int _m = 0; _m < 3; ++_m)                                   \
                ACC_[_m] = __builtin_amdgcn_mfma_f32_16x16x32_f16(           \
                    __builtin_bit_cast(half8, av[_m][_k]),                   \
                    __builtin_bit_cast(half8, BV_[_k]), ACC_[_m], 0, 0, 0);  \
        }                                                                    \
    } while (0)

    float preg16 = 0.f, preg48 = 0.f;

    #define EPI(ACC_, L_) do {                                               \
        float _h0l = fminf(ACC_[0][0], ACC_[0][1]);                          \
        float _h0h = fminf(ACC_[0][2], ACC_[0][3]);                          \
        float _h1l = fminf(ACC_[1][0], ACC_[1][1]);                          \
        float _h1h = fminf(ACC_[1][2], ACC_[1][3]);                          \
        float _h2l = fminf(ACC_[2][0], ACC_[2][1]);                          \
        float _h2h = fminf(ACC_[2][2], ACC_[2][3]);                          \
        float _f0 = fminf(_h0l, _h0h);                                       \
        float _f1 = fminf(_h1l, _h1h);                                       \
        float _f2 = fminf(_h2l, _h2h);                                       \
        float _u16 = (q==0) ? _h1h : (q==1) ? _h0l : (q==2) ? _h2h : _h1l;   \
        float _u48 = (q==0) ? _h1l : (q==1) ? _h0h : (q==2) ? _h2l : _h1h;   \
        float _F16 = (q==0) ? _f0 : (q==3) ? _f2 : _f1;                      \
        float _F48 = (q<=1) ? _f2 : _f0;                                     \
        float _v16 = fminf(_F16, __shfl_xor(_u16, 16));                      \
        float _v48 = fminf(_F48, __shfl_xor(_u48, 48));                      \
        float _vp16 = _v16 + __shfl_xor(_v16, 1);                            \
        float _vp48 = _v48 + __shfl_xor(_v48, 1);                            \
        float2 _gf = gbfw2[(nbase + PHYS(L_)*16 + cx) >> 1];                 \
        if ((cx & 1) == 0) {                                                 \
            preg16 += fmaxf(_vp16 + _gf.x, 0.f) * _gf.y;                     \
            preg48 += fmaxf(_vp48 + _gf.x, 0.f) * _gf.y;                     \
        }                                                                    \
    } while (0)

    f32x4 bv0[7], bv1[7];
    f32x4 acc[3];

    LOADT(bv0, 0);
    // steps L = 0..37: LOAD(L+1 into other bank) | MFMA(L) | EPI(L)
    for (int k = 0; k < 19; ++k) {
        int L = 2*k;
        LOADT(bv1, L + 1); MFMAT(bv0, acc); EPI(acc, L);
        LOADT(bv0, L + 2); MFMAT(bv1, acc); EPI(acc, L + 1);
    }

    preg16 += __shfl_xor(preg16, 1); preg16 += __shfl_xor(preg16, 2);
    preg16 += __shfl_xor(preg16, 4); preg16 += __shfl_xor(preg16, 8);
    preg48 += __shfl_xor(preg48, 1); preg48 += __shfl_xor(preg48, 2);
    preg48 += __shfl_xor(preg48, 4); preg48 += __shfl_xor(preg48, 8);
    if (cx == 0) {
        int b16 = (q==0) ? 0 : (q==1) ? 3 : (q==2) ? 4 : 7;
        int b48 = (q==0) ? 5 : (q==1) ? 6 : (q==2) ? 1 : 2;
        atomicAdd(&out[blockIdx.x*8 + b16], preg16);
        atomicAdd(&out[blockIdx.x*8 + b48], preg48);
    }
}

extern "C" void kernel_launch(void* const* d_in, const int* in_sizes, int n_in,
                              void* d_out, int out_size, void* d_ws, size_t ws_size,
                              hipStream_t stream)
{
    const int*   x   = (const int*)  d_in[0];
    const float* er  = (const float*)d_in[1];
    const float* ev  = (const float*)d_in[2];
    const float* cw  = (const float*)d_in[3];
    const float* cb  = (const float*)d_in[4];
    const float* gam = (const float*)d_in[5];
    const float* bet = (const float*)d_in[6];
    const float* gW  = (const float*)d_in[7];
    const float* gb  = (const float*)d_in[8];
    const float* fW  = (const float*)d_in[9];
    const float* fb  = (const float*)d_in[10];

    float* ws = (float*)d_ws;
    _Float16* m_raw = (_Float16*)(ws + MRAW_OFF);
    _Float16* W_h   = (_Float16*)(ws + WH_OFF);
    _Float16* wT    = (_Float16*)(ws + WT_OFF);
    float* gshad    = ws + STAT_OFF;
    float* out      = (float*)d_out;

    k0_prep<<<(K0_TOT + 255)/256, 256, 0, stream>>>(cw, gW, fb, wT, W_h, out, gshad);
    k1_mfma<<<NROWS/32, 256, 0, stream>>>(x, er, ev, wT, cb, m_raw, gshad);
    k3_mfma<<<NROWS/48, 256, 0, stream>>>(m_raw, gshad, gam, bet, W_h, gb, fW, out);
}